// Round 1
// baseline (67915.662 us; speedup 1.0000x reference)
//
#include <hip/hip_runtime.h>
#include <hip/hip_bf16.h>
#include <cstdint>
#include <cstddef>

// Net: B=256, D=512, L=8, H=8, T=71->64, DH=64.
// Round 0: correct f32 baseline. All heavy compute on vector ALU.
// ws layout (floats): X71 (B*512*71) | X64 (B*512*64) | T1 (B*1024*64, layer tmp
// uses first half; final co1 output uses the whole region). Total ~138 MB.

__device__ __forceinline__ float lrelu(float v) { return v > 0.f ? v : 0.2f * v; }

// ---------------------------------------------------------------------------
// Stage 1: embeddings + LayerNorm over T=71. One thread per (b,d), two passes.
// Output X71[b][d][t]  (B,512,71)
// ---------------------------------------------------------------------------
__global__ __launch_bounds__(256) void build_ln_kernel(
    const int* __restrict__ fen, const int* __restrict__ move,
    const float* __restrict__ rank_emb, const float* __restrict__ file_emb,
    const float* __restrict__ fen_emb, const float* __restrict__ move_emb,
    const float* __restrict__ abs_emb, const float* __restrict__ lnw,
    const float* __restrict__ lnb, float* __restrict__ X71)
{
  const int gid = blockIdx.x * 256 + threadIdx.x;   // < 256*512
  const int b = gid >> 9, d = gid & 511;
  const int* fb = fen + b * 133;

  float sum = 0.f, sq = 0.f, mu = 0.f, rstd = 0.f;
  #pragma unroll 1
  for (int pass = 0; pass < 2; ++pass) {
    if (pass) {
      mu = sum * (1.f / 71.f);
      float var = sq * (1.f / 71.f) - mu * mu;
      rstd = rsqrtf(var + 1e-5f);
    }
    #pragma unroll 1
    for (int t = 0; t < 71; ++t) {
      float a = abs_emb[t * 512 + d];
      float v;
      if (t < 64) {
        float pos = rank_emb[(t >> 3) * 512 + d] + file_emb[(t & 7) * 512 + d];
        v = 0.5f * (fen_emb[fb[t] * 512 + d] + fen_emb[fb[64 + t] * 512 + d] + pos) + a;
      } else if (t < 69) {
        // fen index 128 + (t-64) == t + 64
        v = fen_emb[fb[t + 64] * 512 + d] + a;
      } else {
        int j = t - 69;
        int s = move[b * 2 + j];
        float pos = rank_emb[(s >> 3) * 512 + d] + file_emb[(s & 7) * 512 + d];
        v = (pos + move_emb[j * 512 + d]) * 0.58f + a;
      }
      if (pass) X71[(size_t)gid * 71 + t] = (v - mu) * rstd * lnw[t] + lnb[t];
      else { sum += v; sq += v * v; }
    }
  }
}

// ---------------------------------------------------------------------------
// Fused MHA: per-(b,h) block. lrelu(x) -> QKV gemm (weights staged in LDS) ->
// RMS over token axis -> softmax(QK^T/8) -> PV. Writes y (B,512,64).
// qkv LDS rows padded to 65 floats: bank = (row+lane)%32, conflict-free.
// ---------------------------------------------------------------------------
template <int T>
__global__ __launch_bounds__(256) void mha_kernel(
    const float* __restrict__ x,   // (B,512,T)
    const float* __restrict__ w,   // (3,8,512,64)
    const float* __restrict__ nw,  // scalar rms weight
    float* __restrict__ y)         // (B,512,64)
{
  const int b = blockIdx.x >> 3;
  const int h = blockIdx.x & 7;
  const int tid = threadIdx.x;
  const int lane = tid & 63;
  const int wv = tid >> 6;

  __shared__ float qkv[3 * T * 65];
  __shared__ float wl[3 * 16 * 64];   // [n][dc][dh] for current 16-d chunk
  __shared__ float xs[16 * T];        // lrelu(x) chunk [dc][t]
  __shared__ float scale[192];
  __shared__ float plds[64 * (T + 1)];

  for (int i = tid; i < 3 * T * 65; i += 256) qkv[i] = 0.f;
  __syncthreads();

  const float* wh = w + (size_t)h * 512 * 64;
  for (int c0 = 0; c0 < 512; c0 += 16) {
    for (int i = tid; i < 16 * T; i += 256) {
      int dc = i / T, t = i - dc * T;
      xs[i] = lrelu(x[((size_t)b * 512 + c0 + dc) * T + t]);
    }
    for (int i = tid; i < 3 * 16 * 64; i += 256) {
      int n = i >> 10;
      int rem = i & 1023;
      int dc = rem >> 6, dh = rem & 63;
      wl[i] = wh[((size_t)n * 8 * 512 + c0 + dc) * 64 + dh];
    }
    __syncthreads();
    for (int n = 0; n < 3; ++n) {
      for (int tb = wv * 4; tb < T; tb += 16) {
        const int t1 = (tb + 1 < T) ? tb + 1 : T - 1;
        const int t2 = (tb + 2 < T) ? tb + 2 : T - 1;
        const int t3 = (tb + 3 < T) ? tb + 3 : T - 1;
        float a0 = 0.f, a1 = 0.f, a2 = 0.f, a3 = 0.f;
        #pragma unroll
        for (int dc = 0; dc < 16; ++dc) {
          float wvv = wl[(n * 16 + dc) * 64 + lane];
          a0 += xs[dc * T + tb] * wvv;
          a1 += xs[dc * T + t1] * wvv;
          a2 += xs[dc * T + t2] * wvv;
          a3 += xs[dc * T + t3] * wvv;
        }
        qkv[(n * T + tb) * 65 + lane] += a0;
        if (tb + 1 < T) qkv[(n * T + tb + 1) * 65 + lane] += a1;
        if (tb + 2 < T) qkv[(n * T + tb + 2) * 65 + lane] += a2;
        if (tb + 3 < T) qkv[(n * T + tb + 3) * 65 + lane] += a3;
      }
    }
    __syncthreads();
  }

  // RMS over token axis per (n, dh)
  if (tid < 192) {
    int n = tid >> 6, dh = tid & 63;
    float ss = 0.f;
    for (int t = 0; t < T; ++t) { float v = qkv[(n * T + t) * 65 + dh]; ss += v * v; }
    scale[tid] = nw[0] * rsqrtf(ss * (1.f / T) + 1e-6f);
  }
  __syncthreads();
  for (int i = tid; i < 3 * T * 64; i += 256) {
    int n = i / (T * 64);
    int rem = i - n * T * 64;
    int t = rem >> 6, dh = rem & 63;
    qkv[(n * T + t) * 65 + dh] *= scale[n * 64 + dh];
  }
  __syncthreads();

  const float* qm = qkv;
  const float* km = qkv + T * 65;
  const float* vm = qkv + 2 * T * 65;

  // scores + softmax, query rows t < 64 (only those feed the output slice)
  for (int t = wv; t < 64; t += 4) {
    float s0 = 0.f, s1 = 0.f;
    #pragma unroll 8
    for (int dh = 0; dh < 64; ++dh) {
      s0 += qm[t * 65 + dh] * km[lane * 65 + dh];
    }
    bool has1 = false;
    if constexpr (T > 64) {
      has1 = (lane + 64 < T);
      if (has1) {
        #pragma unroll 8
        for (int dh = 0; dh < 64; ++dh)
          s1 += qm[t * 65 + dh] * km[(lane + 64) * 65 + dh];
      }
    }
    s0 *= 0.125f;
    s1 *= 0.125f;
    float mx = has1 ? fmaxf(s0, s1) : s0;
    #pragma unroll
    for (int off = 32; off; off >>= 1) mx = fmaxf(mx, __shfl_xor(mx, off));
    float e0 = __expf(s0 - mx);
    float e1 = has1 ? __expf(s1 - mx) : 0.f;
    float sm = e0 + e1;
    #pragma unroll
    for (int off = 32; off; off >>= 1) sm += __shfl_xor(sm, off);
    float inv = 1.f / sm;
    plds[t * (T + 1) + lane] = e0 * inv;
    if constexpr (T > 64) {
      if (lane < T - 64) plds[t * (T + 1) + 64 + lane] = e1 * inv;
    }
  }
  __syncthreads();

  // out[b, h*64+dh, t] = sum_j p[t][j] * v[j][dh]
  float* yb = y + ((size_t)b * 512 + h * 64 + lane) * 64;
  for (int t = wv; t < 64; t += 4) {
    float acc = 0.f;
    #pragma unroll 8
    for (int j = 0; j < T; ++j)
      acc += plds[t * (T + 1) + j] * vm[j * 65 + lane];
    yb[t] = acc;
  }
}

// ---------------------------------------------------------------------------
// dst[r][t] = a[r][t (stride aStride)] + bsrc[r][t]; grid covers B*512*64.
// ---------------------------------------------------------------------------
__global__ __launch_bounds__(256) void add_slice_kernel(
    float* __restrict__ dst, const float* __restrict__ a, int aStride,
    const float* __restrict__ bsrc)
{
  size_t gid = (size_t)blockIdx.x * 256 + threadIdx.x;
  size_t r = gid >> 6;
  int t = (int)(gid & 63);
  dst[gid] = a[r * aStride + t] + bsrc[gid];
}

// ---------------------------------------------------------------------------
// 3x3 SAME conv on 8x8, lrelu applied to input. Block = (b, 64-oc tile).
// LDS: 16-channel input chunk + weights for the chunk. acc[16] per thread.
// Optional residual added in the epilogue.
// ---------------------------------------------------------------------------
__global__ __launch_bounds__(256) void conv3x3_kernel(
    const float* __restrict__ x,    // (B, CIN, 64)
    const float* __restrict__ w,    // (COUT, CIN, 9)
    const float* __restrict__ bias, // (COUT)
    const float* __restrict__ res,  // residual (B, COUT, 64) or nullptr
    float* __restrict__ out,        // (B, COUT, 64)
    int CIN, int COUT)
{
  const int nt = COUT >> 6;
  const int b = blockIdx.x / nt;
  const int ot = blockIdx.x - b * nt;
  const int tid = threadIdx.x;
  const int p = tid & 63;
  const int wg = tid >> 6;
  const int i0 = p >> 3, j0 = p & 7;

  __shared__ float xs[16 * 64];
  __shared__ float wl[64 * 16 * 9];

  float acc[16];
  #pragma unroll
  for (int i = 0; i < 16; ++i) acc[i] = bias[ot * 64 + wg * 16 + i];

  for (int c0 = 0; c0 < CIN; c0 += 16) {
    for (int idx = tid; idx < 1024; idx += 256) {
      int c = idx >> 6, pp = idx & 63;
      xs[idx] = lrelu(x[((size_t)b * CIN + c0 + c) * 64 + pp]);
    }
    for (int idx = tid; idx < 9216; idx += 256) {
      int o = idx / 144, rem = idx - o * 144;
      wl[idx] = w[((size_t)(ot * 64 + o) * CIN + c0) * 9 + rem];
    }
    __syncthreads();
    #pragma unroll
    for (int k = 0; k < 9; ++k) {
      const int dy = k / 3 - 1, dx = k - (k / 3) * 3 - 1;
      const int ii = i0 + dy, jj = j0 + dx;
      const bool valid = ((unsigned)ii < 8u) && ((unsigned)jj < 8u);
      const int np = ii * 8 + jj;
      #pragma unroll 4
      for (int c = 0; c < 16; ++c) {
        float xv = valid ? xs[c * 64 + np] : 0.f;
        const float* wp = &wl[(wg * 16) * 144 + c * 9 + k];
        #pragma unroll
        for (int i = 0; i < 16; ++i)
          acc[i] += xv * wp[i * 144];
      }
    }
    __syncthreads();
  }
  #pragma unroll
  for (int i = 0; i < 16; ++i) {
    int o = ot * 64 + wg * 16 + i;
    size_t idx = ((size_t)b * COUT + o) * 64 + p;
    float v = acc[i];
    if (res) v += res[idx];
    out[idx] = v;
  }
}

// ---------------------------------------------------------------------------
// RMS over the 64 spatial positions per (b, channel) row, in place.
// ---------------------------------------------------------------------------
__global__ __launch_bounds__(256) void rms_spatial_kernel(
    float* __restrict__ y, const float* __restrict__ nw, int nrows)
{
  int gid = blockIdx.x * 256 + threadIdx.x;
  if (gid >= nrows) return;
  float* row = y + (size_t)gid * 64;
  float ss = 0.f;
  #pragma unroll 8
  for (int p = 0; p < 64; ++p) { float v = row[p]; ss += v * v; }
  float sc = nw[0] * rsqrtf(ss * (1.f / 64.f) + 1e-6f);
  #pragma unroll 8
  for (int p = 0; p < 64; ++p) row[p] *= sc;
}

// ---------------------------------------------------------------------------
// Final VALID 8x8 conv: out[b] = sum_{c,p} lrelu(F1[b,c,p]) * w[c,p] + bias.
// ---------------------------------------------------------------------------
__global__ __launch_bounds__(256) void co2_kernel(
    const float* __restrict__ xf,  // (B, 1024, 64)
    const float* __restrict__ w,   // (1024*64)
    const float* __restrict__ cb,  // scalar
    float* __restrict__ out)
{
  const int b = blockIdx.x, tid = threadIdx.x;
  const float* xb = xf + (size_t)b * 65536;
  float acc = 0.f;
  for (int i = tid; i < 65536; i += 256)
    acc += lrelu(xb[i]) * w[i];
  #pragma unroll
  for (int off = 32; off; off >>= 1) acc += __shfl_down(acc, off);
  __shared__ float red[4];
  if ((tid & 63) == 0) red[tid >> 6] = acc;
  __syncthreads();
  if (tid == 0) out[b] = red[0] + red[1] + red[2] + red[3] + cb[0];
}

// ---------------------------------------------------------------------------
extern "C" void kernel_launch(void* const* d_in, const int* in_sizes, int n_in,
                              void* d_out, int out_size, void* d_ws, size_t ws_size,
                              hipStream_t stream)
{
  const int*   fen        = (const int*)d_in[0];
  const int*   move       = (const int*)d_in[1];
  const float* rank_emb   = (const float*)d_in[2];
  const float* file_emb   = (const float*)d_in[3];
  const float* fen_emb    = (const float*)d_in[4];
  const float* move_emb   = (const float*)d_in[5];
  const float* abs_emb    = (const float*)d_in[6];
  const float* ln_w       = (const float*)d_in[7];
  const float* ln_b       = (const float*)d_in[8];
  const float* emb_qkv    = (const float*)d_in[9];
  const float* emb_norm_w = (const float*)d_in[10];
  const float* qkv        = (const float*)d_in[11];
  const float* mha_norm_w = (const float*)d_in[12];
  const float* conv1_w    = (const float*)d_in[13];
  const float* conv1_b    = (const float*)d_in[14];
  const float* conv2_w    = (const float*)d_in[15];
  const float* conv2_b    = (const float*)d_in[16];
  const float* cb_norm_w  = (const float*)d_in[17];
  const float* out_norm_w = (const float*)d_in[18];
  const float* co1_w      = (const float*)d_in[19];
  const float* co1_b      = (const float*)d_in[20];
  const float* co2_w      = (const float*)d_in[21];
  const float* co2_b      = (const float*)d_in[22];
  float* out = (float*)d_out;

  float* ws  = (float*)d_ws;
  float* X71 = ws;                               // 256*512*71 = 9,306,112
  float* X64 = X71 + (size_t)256 * 512 * 71;     // 256*512*64 = 8,388,608
  float* T1  = X64 + (size_t)256 * 512 * 64;     // 16,777,216 (layer tmp / co1 out)
  float* F1  = T1;

  // embeddings + layernorm
  build_ln_kernel<<<512, 256, 0, stream>>>(fen, move, rank_emb, file_emb,
                                           fen_emb, move_emb, abs_emb,
                                           ln_w, ln_b, X71);
  // embedding MHA (T=71), then x = x[:, :, :64] + y[:, :, :64]
  mha_kernel<71><<<2048, 256, 0, stream>>>(X71, emb_qkv, emb_norm_w, T1);
  add_slice_kernel<<<32768, 256, 0, stream>>>(X64, X71, 71, T1);

  for (int l = 0; l < 8; ++l) {
    const float* w1 = conv1_w + (size_t)l * 512 * 512 * 9;
    const float* w2 = conv2_w + (size_t)l * 512 * 512 * 9;
    // conv block: conv1 -> rms(spatial) -> conv2 (+residual into X64)
    conv3x3_kernel<<<2048, 256, 0, stream>>>(X64, w1, conv1_b + l * 512,
                                             nullptr, T1, 512, 512);
    rms_spatial_kernel<<<512, 256, 0, stream>>>(T1, cb_norm_w + l, 256 * 512);
    conv3x3_kernel<<<2048, 256, 0, stream>>>(T1, w2, conv2_b + l * 512,
                                             X64, X64, 512, 512);
    // MHA + residual
    mha_kernel<64><<<2048, 256, 0, stream>>>(X64, qkv + (size_t)l * 3 * 8 * 512 * 64,
                                             mha_norm_w + l, T1);
    add_slice_kernel<<<32768, 256, 0, stream>>>(X64, X64, 64, T1);
  }

  // head: co1 (512->1024 SAME) -> rms(spatial) -> co2 (VALID 8x8 -> scalar)
  conv3x3_kernel<<<4096, 256, 0, stream>>>(X64, co1_w, co1_b, nullptr, F1, 512, 1024);
  rms_spatial_kernel<<<1024, 256, 0, stream>>>(F1, out_norm_w, 256 * 1024);
  co2_kernel<<<256, 256, 0, stream>>>(F1, co2_w, co2_b, out);
}